// Round 11
// baseline (272.881 us; speedup 1.0000x reference)
//
#include <hip/hip_runtime.h>
#include <hip/hip_bf16.h>
#include <stdint.h>

// Problem constants (from reference)
#define B_N     2048
#define E_N     32
#define IN_N    2048
#define OUT_N   1024
#define TOPK    4

// GEMM tiling (R4's healthy geometry + bf16-A)
#define BM      256
#define BN      128
#define BK      32
#define NT      (OUT_N / BN)        // 8 n-tiles
#define NKT     (IN_N / BK)         // 64 k-steps
#define THREADS 512                 // 8 waves 2m x 4n, wave tile 128x32
#define MAX_SLOTS 64                // sum ceil(c_e/256) <= 8192/256+32 = 64
#define GRID_GEMM (MAX_SLOTS * NT)  // 512

// ws layout
#define WS_COUNTS 0     // [32] ints
#define WS_NSLOTS 32    // [1]
#define WS_DESC   64    // [MAX_SLOTS]  packed (e<<6)|mt
#define WS_LISTS  256   // [E_N][B_N]   packed (b<<2)|k
#define FEATB_OFF 264192  // byte offset of bf16 feat copy (8.4MB)

typedef float  f32x4  __attribute__((ext_vector_type(4)));
typedef __bf16 bf16x8 __attribute__((ext_vector_type(8)));

union Pack8 { bf16x8 v; uint4 u; };

__device__ __forceinline__ uint4 pack8(f32x4 lo, f32x4 hi) {
  Pack8 p;
#pragma unroll
  for (int j = 0; j < 4; ++j) { p.v[j] = (__bf16)lo[j]; p.v[j + 4] = (__bf16)hi[j]; }
  return p.u;
}
__device__ __forceinline__ bf16x8 as_frag(uint4 u) { Pack8 p; p.u = u; return p.v; }

// ---------------- kernel 0: zero counters ----------------
__global__ void k_zero(int* __restrict__ ws) {
  if (threadIdx.x < 64) ws[threadIdx.x] = 0;
}

// ---------------- kernel 0b: feat f32 -> bf16 ----------------
__global__ void k_conv(const float* __restrict__ f, unsigned short* __restrict__ o) {
  int i = (blockIdx.x * 256 + threadIdx.x) * 8;
  f32x4 a = *(const f32x4*)(f + i);
  f32x4 b = *(const f32x4*)(f + i + 4);
  *(uint4*)(o + i) = pack8(a, b);
}

// ---------------- kernel 1: top-4-smallest + bucket ----------------
__global__ void k_topk(const float* __restrict__ act, int* __restrict__ ws) {
  int b = blockIdx.x * blockDim.x + threadIdx.x;
  if (b >= B_N) return;
  float v[E_N];
  const float* a = act + (size_t)b * E_N;
#pragma unroll
  for (int e = 0; e < E_N; ++e) v[e] = a[e];
  unsigned chosen = 0;
#pragma unroll
  for (int k = 0; k < TOPK; ++k) {
    float mv = 3.4e38f; int mi = 0;
#pragma unroll
    for (int e = 0; e < E_N; ++e) {
      bool sel = (((chosen >> e) & 1u) == 0u) && (v[e] < mv);  // strict <: stable
      mv = sel ? v[e] : mv;
      mi = sel ? e : mi;
    }
    chosen |= (1u << mi);
    int pos = atomicAdd(&ws[WS_COUNTS + mi], 1);
    ws[WS_LISTS + mi * B_N + pos] = (b << 2) | k;
  }
}

// ---------------- kernel 2: build tile worklist ----------------
__global__ void k_tiles(int* __restrict__ ws) {
  int e = threadIdx.x;  // one wave of 64
  int c = (e < E_N) ? ws[WS_COUNTS + e] : 0;
  int t = (c + BM - 1) / BM;
  int off = 0, tot = 0;
  for (int j = 0; j < E_N; ++j) {
    int tj = __shfl(t, j, 64);
    if (j < e) off += tj;
    tot += tj;
  }
  if (e < E_N) {
    for (int i = 0; i < t; ++i) ws[WS_DESC + off + i] = (e << 6) | i;
  }
  if (e == 0) ws[WS_NSLOTS] = tot;
}

// ---------------- kernel 3: grouped GEMM (bf16 MFMA) ----------------
// 256x128 block tile, BK=32, reg prefetch + LDS dbuf, 1 barrier/K-step.
// A loaded as bf16 uint4 from featb (halves A staging bytes vs f32).
// 8 waves 2m x 4n; wave tile 128x32 (8x2 fragments).
__global__ __launch_bounds__(THREADS, 2)
void k_gemm(const unsigned short* __restrict__ featb, const float* __restrict__ Wm,
            const float* __restrict__ bias, const int* __restrict__ ws,
            float* __restrict__ out) {
  int p = blockIdx.x;
  int j = p >> 3;
  int slot = (p & 7) + ((j >> 3) << 3);  // slot % 8 == p % 8; bijective
  int nt   = j & 7;
  if (slot >= ws[WS_NSLOTS]) return;
  int desc = ws[WS_DESC + slot];
  int e = desc >> 6, mt = desc & 63;
  int count = ws[WS_COUNTS + e];
  int m0 = mt * BM;

  // LDS per buffer: A 1024 + W 512 uint4 slots (24KB); dbuf = 48KB
  __shared__ uint4 lds4[3072];
  __shared__ int gids[BM];

  int tid  = threadIdx.x;
  int lane = tid & 63;
  int wv   = tid >> 6;
  int wm   = wv >> 2;   // 0..1
  int wn   = wv & 3;    // 0..3

  // --- A staging: 2 threads/row, 2 uint4 (32 bf16 = 64B) each ---
  int arow = tid >> 1, ah = tid & 1;
  int gid = -1;
  if (m0 + arow < count) gid = ws[WS_LISTS + e * B_N + m0 + arow];
  if (ah == 0) gids[arow] = gid;
  const unsigned short* aptr =
      featb + (size_t)((gid >= 0) ? (gid >> 2) : 0) * IN_N + ah * 16;
  int a_wi0 = arow * 4 + ((ah * 2)     ^ ((arow >> 1) & 3));
  int a_wi1 = arow * 4 + ((ah * 2 + 1) ^ ((arow >> 1) & 3));

  // --- W staging: 4 threads/row, 8 floats each -> 1 slot ---
  int wrow = tid >> 2, kq = tid & 3;
  const float* wptr = Wm + ((size_t)e * OUT_N + (size_t)(nt * BN + wrow)) * IN_N + kq * 8;
  int w_wi = 1024 + wrow * 4 + (kq ^ ((wrow >> 1) & 3));

  // --- fragment read indices (uint4 units, swizzled) ---
  int aidx[8], bidx[2];
#pragma unroll
  for (int mi = 0; mi < 8; ++mi) {
    int r = wm * 128 + mi * 16 + (lane & 15);
    aidx[mi] = r * 4 + ((lane >> 4) ^ ((r >> 1) & 3));
  }
#pragma unroll
  for (int ni = 0; ni < 2; ++ni) {
    int r = wn * 32 + ni * 16 + (lane & 15);
    bidx[ni] = 1024 + r * 4 + ((lane >> 4) ^ ((r >> 1) & 3));
  }

  uint4 ra[2];
  f32x4 rw[2];

#define LOAD_TILE(K0)                                                        \
  do {                                                                       \
    ra[0] = *(const uint4*)(aptr + (K0));                                    \
    ra[1] = *(const uint4*)(aptr + (K0) + 8);                                \
    rw[0] = *(const f32x4*)(wptr + (K0));                                    \
    rw[1] = *(const f32x4*)(wptr + (K0) + 4);                                \
  } while (0)

#define WRITE_TILE(BUF)                                                      \
  do {                                                                       \
    lds4[(BUF) * 1536 + a_wi0] = ra[0];                                      \
    lds4[(BUF) * 1536 + a_wi1] = ra[1];                                      \
    lds4[(BUF) * 1536 + w_wi]  = pack8(rw[0], rw[1]);                        \
  } while (0)

  f32x4 acc[8][2] = {};  // [mi][ni]

  LOAD_TILE(0);
  WRITE_TILE(0);
  __syncthreads();

  int cur = 0;
#pragma unroll 1
  for (int kt = 0; kt < NKT; ++kt) {
    bool pf = (kt + 1 < NKT);
    if (pf) LOAD_TILE((kt + 1) * BK);   // issue next tile's loads first

    int base = cur * 1536;
    bf16x8 af[8], bfr[2];
#pragma unroll
    for (int mi = 0; mi < 8; ++mi) af[mi] = as_frag(lds4[base + aidx[mi]]);
#pragma unroll
    for (int ni = 0; ni < 2; ++ni) bfr[ni] = as_frag(lds4[base + bidx[ni]]);
#pragma unroll
    for (int mi = 0; mi < 8; ++mi)
#pragma unroll
      for (int ni = 0; ni < 2; ++ni)
        acc[mi][ni] = __builtin_amdgcn_mfma_f32_16x16x32_bf16(af[mi], bfr[ni], acc[mi][ni], 0, 0, 0);

    if (pf) WRITE_TILE(cur ^ 1);        // other buffer
    __syncthreads();                    // writes landed + all done reading cur
    cur ^= 1;
  }

  // --- epilogue: D row=(lane>>4)*4+j, col=lane&15 ---
#pragma unroll
  for (int ni = 0; ni < 2; ++ni) {
    int col = nt * BN + wn * 32 + ni * 16 + (lane & 15);
    float bs = bias[e * OUT_N + col];
#pragma unroll
    for (int mi = 0; mi < 8; ++mi) {
#pragma unroll
      for (int j2 = 0; j2 < 4; ++j2) {
        int g = gids[wm * 128 + mi * 16 + (lane >> 4) * 4 + j2];
        if (g >= 0) out[(size_t)g * OUT_N + col] = acc[mi][ni][j2] + bs;
      }
    }
  }
}

extern "C" void kernel_launch(void* const* d_in, const int* in_sizes, int n_in,
                              void* d_out, int out_size, void* d_ws, size_t ws_size,
                              hipStream_t stream) {
  const float* feat = (const float*)d_in[0];   // [B, IN]
  const float* Wm   = (const float*)d_in[1];   // [E, OUT, IN]
  const float* bias = (const float*)d_in[2];   // [E, OUT]
  const float* act  = (const float*)d_in[3];   // [B, E]
  int*   ws  = (int*)d_ws;
  unsigned short* featb = (unsigned short*)((char*)d_ws + FEATB_OFF);
  float* out = (float*)d_out;

  hipLaunchKernelGGL(k_zero,  dim3(1),                 dim3(64),      0, stream, ws);
  hipLaunchKernelGGL(k_conv,  dim3(B_N * IN_N / 2048), dim3(256),     0, stream, feat, featb);
  hipLaunchKernelGGL(k_topk,  dim3(B_N / 256),         dim3(256),     0, stream, act, ws);
  hipLaunchKernelGGL(k_tiles, dim3(1),                 dim3(64),      0, stream, ws);
  hipLaunchKernelGGL(k_gemm,  dim3(GRID_GEMM),         dim3(THREADS), 0, stream,
                     featb, Wm, bias, ws, out);
}